// Round 14
// baseline (380.266 us; speedup 1.0000x reference)
//
#include <hip/hip_runtime.h>
#include <math.h>

#define CDIM 2048
#define EDIM 64
#define BM   32
#define NITW 16           // per-wave iterations of BK=32 over its 512-k segment
#define PREPB 32
#define DIAG_REPS 3       // extra dummy K-passes (diagnostic load amplification)

// scales keep fp16 "lo" parts normal; product scale = 2^22
#define SCALE_H 1024.0f
#define SCALE_W 4096.0f
#define INV_SCALE (1.0f / 4194304.0f)

typedef float    f32x16 __attribute__((ext_vector_type(16)));
typedef float    f32x4  __attribute__((ext_vector_type(4)));
typedef _Float16 f16x8  __attribute__((ext_vector_type(8)));
typedef __fp16   cvt_t  __attribute__((ext_vector_type(2)));

// ---- prep: 32 blocks x 64 k-rows (identical to R9)
__global__ void prep_w(const float* __restrict__ W,
                       unsigned short* __restrict__ bfrag,
                       float* __restrict__ pnw) {
    __shared__ float tile[64][65];
    __shared__ float part[4][64];
    const int t = threadIdx.x;            // 256
    const int c0 = blockIdx.x * 64;
#pragma unroll
    for (int p = 0; p < 4; ++p) {
        int r = (t >> 4) + p * 16;
        float4 v = *reinterpret_cast<const float4*>(W + (size_t)(c0 + r) * EDIM + (t & 15) * 4);
        tile[r][(t & 15) * 4 + 0] = v.x;
        tile[r][(t & 15) * 4 + 1] = v.y;
        tile[r][(t & 15) * 4 + 2] = v.z;
        tile[r][(t & 15) * 4 + 3] = v.w;
    }
    __syncthreads();
    {
        int g = t >> 6, e = t & 63;
        float s = 0.f;
#pragma unroll
        for (int j = 0; j < 16; ++j) { float v = tile[g * 16 + j][e]; s += v * v; }
        part[g][e] = s;
    }
    __syncthreads();
    if (t < 64) pnw[blockIdx.x * EDIM + t] = part[0][t] + part[1][t] + part[2][t] + part[3][t];
    const int nt = t >> 7, hl = (t >> 6) & 1, lane = t & 63;
    const int e = nt * 32 + (lane & 31);
    const int kb = (lane >> 5) * 8;
#pragma unroll
    for (int s = 0; s < 4; ++s) {
        int kl = s * 16 + kb;
        unsigned int wds[4];
#pragma unroll
        for (int pj = 0; pj < 4; ++pj) {
            float v0 = tile[kl + 2 * pj][e] * SCALE_W;
            float v1 = tile[kl + 2 * pj + 1][e] * SCALE_W;
            cvt_t hh = __builtin_amdgcn_cvt_pkrtz(v0, v1);
            if (hl) {
                cvt_t ll = __builtin_amdgcn_cvt_pkrtz(v0 - (float)hh[0], v1 - (float)hh[1]);
                wds[pj] = __builtin_bit_cast(unsigned int, ll);
            } else {
                wds[pj] = __builtin_bit_cast(unsigned int, hh);
            }
        }
        size_t off = ((size_t)(blockIdx.x * 4 + s)) * 2048 + (size_t)nt * 1024 + (size_t)hl * 512 + (size_t)lane * 8;
        *reinterpret_cast<uint4*>(bfrag + off) = make_uint4(wds[0], wds[1], wds[2], wds[3]);
    }
}

template<int BUF>
__device__ __forceinline__ void stageA(int it, int w, int l, int row0,
    const float* __restrict__ H, float (&aS)[4][2][32][32]) {
#pragma unroll
    for (int J = 0; J < 4; ++J) {
        const int row_ = 8 * J + (l >> 3);
        const float* src = H + (size_t)(row0 + row_) * CDIM + w * 512 + it * 32
                         + (((l & 7) ^ (row_ & 7)) << 2);
        __builtin_amdgcn_global_load_lds(
            (const __attribute__((address_space(1))) unsigned int*)src,
            (__attribute__((address_space(3))) unsigned int*)&aS[w][BUF][8 * J][0], 16, 0, 0);
    }
}

__device__ __forceinline__ void loadB(int it, int w, int l,
    const unsigned short* __restrict__ bfrag, uint4 (&b)[8]) {
    const int kc0 = w * 32 + it * 2;
#pragma unroll
    for (int kc2 = 0; kc2 < 2; ++kc2)
#pragma unroll
        for (int nt = 0; nt < 2; ++nt)
#pragma unroll
            for (int hl = 0; hl < 2; ++hl)
                b[kc2 * 4 + nt * 2 + hl] = *reinterpret_cast<const uint4*>(
                    bfrag + (size_t)(kc0 + kc2) * 2048 + nt * 1024 + hl * 512 + (size_t)l * 8);
}

// R9 kstep verbatim: loadB(it) -> stageA(it+1) -> vmcnt(4) -> pure compute
template<int BUF, bool LAST>
__device__ __forceinline__ void kstep(int it, int w, int l, int row0,
    const float* __restrict__ H, const unsigned short* __restrict__ bfrag,
    float (&aS)[4][2][32][32], f32x16 (&acc)[2], float& nacc) {
    uint4 bcur[8];
    loadB(it, w, l, bfrag, bcur);
    if (!LAST) stageA<BUF ^ 1>(it + 1, w, l, row0, H, aS);
    __builtin_amdgcn_sched_barrier(0);
    if (LAST) { asm volatile("s_waitcnt vmcnt(0)" ::: "memory"); }
    else      { asm volatile("s_waitcnt vmcnt(4)" ::: "memory"); }
    __builtin_amdgcn_sched_barrier(0);

    const int r = l & 31, kg = l >> 5;
#pragma unroll
    for (int kc2 = 0; kc2 < 2; ++kc2) {
        const int c0 = kc2 * 4 + kg * 2;
        f32x4 a0 = *reinterpret_cast<const f32x4*>(&aS[w][BUF][r][((c0)     ^ (r & 7)) * 4]);
        f32x4 a1 = *reinterpret_cast<const f32x4*>(&aS[w][BUF][r][((c0 + 1) ^ (r & 7)) * 4]);
        float f0 = a0[0], f1 = a0[1], f2 = a0[2], f3 = a0[3];
        float f4 = a1[0], f5 = a1[1], f6 = a1[2], f7 = a1[3];
        nacc += f0*f0 + f1*f1 + f2*f2 + f3*f3 + f4*f4 + f5*f5 + f6*f6 + f7*f7;
        float s0 = f0*SCALE_H, s1 = f1*SCALE_H, s2 = f2*SCALE_H, s3 = f3*SCALE_H;
        float s4 = f4*SCALE_H, s5 = f5*SCALE_H, s6 = f6*SCALE_H, s7 = f7*SCALE_H;
        cvt_t h0 = __builtin_amdgcn_cvt_pkrtz(s0, s1);
        cvt_t h1 = __builtin_amdgcn_cvt_pkrtz(s2, s3);
        cvt_t h2 = __builtin_amdgcn_cvt_pkrtz(s4, s5);
        cvt_t h3 = __builtin_amdgcn_cvt_pkrtz(s6, s7);
        cvt_t l0 = __builtin_amdgcn_cvt_pkrtz(s0 - (float)h0[0], s1 - (float)h0[1]);
        cvt_t l1 = __builtin_amdgcn_cvt_pkrtz(s2 - (float)h1[0], s3 - (float)h1[1]);
        cvt_t l2 = __builtin_amdgcn_cvt_pkrtz(s4 - (float)h2[0], s5 - (float)h2[1]);
        cvt_t l3 = __builtin_amdgcn_cvt_pkrtz(s6 - (float)h3[0], s7 - (float)h3[1]);
        f16x8 ah = __builtin_bit_cast(f16x8, make_uint4(
            __builtin_bit_cast(unsigned int, h0), __builtin_bit_cast(unsigned int, h1),
            __builtin_bit_cast(unsigned int, h2), __builtin_bit_cast(unsigned int, h3)));
        f16x8 al = __builtin_bit_cast(f16x8, make_uint4(
            __builtin_bit_cast(unsigned int, l0), __builtin_bit_cast(unsigned int, l1),
            __builtin_bit_cast(unsigned int, l2), __builtin_bit_cast(unsigned int, l3)));
        f16x8 bh0 = __builtin_bit_cast(f16x8, bcur[kc2 * 4 + 0]);
        f16x8 bl0 = __builtin_bit_cast(f16x8, bcur[kc2 * 4 + 1]);
        f16x8 bh1 = __builtin_bit_cast(f16x8, bcur[kc2 * 4 + 2]);
        f16x8 bl1 = __builtin_bit_cast(f16x8, bcur[kc2 * 4 + 3]);
        acc[0] = __builtin_amdgcn_mfma_f32_32x32x16_f16(ah, bh0, acc[0], 0, 0, 0);
        acc[1] = __builtin_amdgcn_mfma_f32_32x32x16_f16(ah, bh1, acc[1], 0, 0, 0);
        acc[0] = __builtin_amdgcn_mfma_f32_32x32x16_f16(ah, bl0, acc[0], 0, 0, 0);
        acc[1] = __builtin_amdgcn_mfma_f32_32x32x16_f16(ah, bl1, acc[1], 0, 0, 0);
        acc[0] = __builtin_amdgcn_mfma_f32_32x32x16_f16(al, bh0, acc[0], 0, 0, 0);
        acc[1] = __builtin_amdgcn_mfma_f32_32x32x16_f16(al, bh1, acc[1], 0, 0, 0);
    }
}

// one full K-pass over this wave's 512-k segment (R9 main loop verbatim)
__device__ __forceinline__ void kpass(int w, int l, int row0,
    const float* __restrict__ H, const unsigned short* __restrict__ bfrag,
    float (&aS)[4][2][32][32], f32x16 (&acc)[2], float& nacc) {
    stageA<0>(0, w, l, row0, H, aS);
    kstep<0, false>( 0, w, l, row0, H, bfrag, aS, acc, nacc);
    kstep<1, false>( 1, w, l, row0, H, bfrag, aS, acc, nacc);
    kstep<0, false>( 2, w, l, row0, H, bfrag, aS, acc, nacc);
    kstep<1, false>( 3, w, l, row0, H, bfrag, aS, acc, nacc);
    kstep<0, false>( 4, w, l, row0, H, bfrag, aS, acc, nacc);
    kstep<1, false>( 5, w, l, row0, H, bfrag, aS, acc, nacc);
    kstep<0, false>( 6, w, l, row0, H, bfrag, aS, acc, nacc);
    kstep<1, false>( 7, w, l, row0, H, bfrag, aS, acc, nacc);
    kstep<0, false>( 8, w, l, row0, H, bfrag, aS, acc, nacc);
    kstep<1, false>( 9, w, l, row0, H, bfrag, aS, acc, nacc);
    kstep<0, false>(10, w, l, row0, H, bfrag, aS, acc, nacc);
    kstep<1, false>(11, w, l, row0, H, bfrag, aS, acc, nacc);
    kstep<0, false>(12, w, l, row0, H, bfrag, aS, acc, nacc);
    kstep<1, false>(13, w, l, row0, H, bfrag, aS, acc, nacc);
    kstep<0, false>(14, w, l, row0, H, bfrag, aS, acc, nacc);
    kstep<1, true >(15, w, l, row0, H, bfrag, aS, acc, nacc);
}

// ---- main: R9 + DIAG_REPS dummy passes (kept live via asm sink; logits bit-identical)
__launch_bounds__(256, 2)
__global__ void gating_main(const float* __restrict__ H,
                            const unsigned short* __restrict__ bfrag,
                            const float* __restrict__ pnw,
                            const float* __restrict__ gates,
                            float* __restrict__ out_rw,
                            float* __restrict__ out_lg,
                            float* __restrict__ out_mk) {
    __shared__ float aS[4][2][32][32];   // 32 KB; reused as red[4][32][64] after K-loop
    __shared__ float normred[4][32];
    __shared__ float invw_s[64], sig_s[64];

    const int t = threadIdx.x;
    const int w = t >> 6, l = t & 63;
    const int row0 = blockIdx.x * BM;
    const int kg = l >> 5, arow = l & 31;

    f32x16 acc[2];
#pragma unroll
    for (int a = 0; a < 2; ++a)
#pragma unroll
        for (int i = 0; i < 16; ++i) acc[a][i] = 0.f;
    float nacc = 0.f;

    kpass(w, l, row0, H, bfrag, aS, acc, nacc);          // the real pass

    {   // diagnostic passes: same instruction stream, results sunk, not folded in
        f32x16 acc2[2];
#pragma unroll
        for (int a = 0; a < 2; ++a)
#pragma unroll
            for (int i = 0; i < 16; ++i) acc2[a][i] = 0.f;
        float nacc2 = 0.f;
#pragma unroll 1
        for (int rep = 0; rep < DIAG_REPS; ++rep)
            kpass(w, l, row0, H, bfrag, aS, acc2, nacc2);
        float sink = acc2[0][0] + acc2[1][0] + nacc2;
        asm volatile("" :: "v"(sink));
    }

    __syncthreads();                      // all waves' reads done -> reuse aS as red

    float* redp = &aS[0][0][0][0];        // red[(w*32+row)*64 + e]
#pragma unroll
    for (int nt = 0; nt < 2; ++nt)
#pragma unroll
        for (int r = 0; r < 16; ++r) {
            int row = (r & 3) + 8 * (r >> 2) + 4 * kg;   // 32x32 C/D layout
            redp[((size_t)w * 32 + row) * 64 + nt * 32 + arow] = acc[nt][r];
        }
    nacc += __shfl_xor(nacc, 32);
    if (l < 32) normred[w][l] = nacc;
    if (t < 64) {
        float s2 = 0.f;
#pragma unroll
        for (int b = 0; b < PREPB; ++b) s2 += pnw[b * EDIM + t];
        invw_s[t] = 1.f / fmaxf(sqrtf(s2), 1e-12f);
        sig_s[t] = 1.f / (1.f + __expf(-gates[t]));
    }
    __syncthreads();

    // ---- epilogue: 8 threads per row, 8 experts each (validated top-2/count/softmax)
    const int rr = t >> 3, e0 = (t & 7) * 8;
    const int orow = row0 + rr;
    float nh = normred[0][rr] + normred[1][rr] + normred[2][rr] + normred[3][rr];
    float invh = INV_SCALE / fmaxf(sqrtf(nh), 1e-12f);
    float lg[8];
#pragma unroll
    for (int k2 = 0; k2 < 8; ++k2) {
        int ee = e0 + k2;
        float s = redp[(0 * 32 + rr) * 64 + ee] + redp[(1 * 32 + rr) * 64 + ee]
                + redp[(2 * 32 + rr) * 64 + ee] + redp[(3 * 32 + rr) * 64 + ee];
        lg[k2] = s * invh * invw_s[ee] - sig_s[ee];
    }
    float* plg = out_lg + (size_t)orow * EDIM + e0;
    *reinterpret_cast<float4*>(plg)     = make_float4(lg[0], lg[1], lg[2], lg[3]);
    *reinterpret_cast<float4*>(plg + 4) = make_float4(lg[4], lg[5], lg[6], lg[7]);

    float v1 = -INFINITY, v2 = -INFINITY;
    int i1 = 0x7fffffff, i2 = 0x7fffffff, cnt = 0;
#pragma unroll
    for (int j = 0; j < 8; ++j) {
        int ee = e0 + j;
        float v = lg[j];
        cnt += (v > 0.f) ? 1 : 0;
        if (v > v1) { v2 = v1; i2 = i1; v1 = v; i1 = ee; }
        else if (v > v2) { v2 = v; i2 = ee; }
    }
#pragma unroll
    for (int st = 1; st <= 4; st <<= 1) {
        float w1 = __shfl_xor(v1, st);
        int   j1 = __shfl_xor(i1, st);
        float wv2 = __shfl_xor(v2, st);
        int   j2 = __shfl_xor(i2, st);
        int   cc = __shfl_xor(cnt, st);
        cnt += cc;
        bool g = (w1 > v1) || (w1 == v1 && j1 < i1);
        if (g) {
            bool g2 = (v1 > wv2) || (v1 == wv2 && i1 < j2);
            float nv2 = g2 ? v1 : wv2;
            int   ni2 = g2 ? i1 : j2;
            v1 = w1; i1 = j1; v2 = nv2; i2 = ni2;
        } else {
            bool g2 = (w1 > v2) || (w1 == v2 && j1 < i2);
            if (g2) { v2 = w1; i2 = j1; }
        }
    }
    bool act = cnt > 0;
    float rmax = act ? v1 : 0.f;
    float xs[8], ms[8];
    float wsum = 0.f;
#pragma unroll
    for (int j = 0; j < 8; ++j) {
        int ee = e0 + j;
        float lv = lg[j];
        float x, m;
        if (act) {
            bool sel = lv > 0.f;
            m = sel ? 1.f : 0.f;
            x = sel ? __expf(lv - rmax) : 0.f;
        } else {
            bool sel = (ee == i1) || (ee == i2);
            m = sel ? 1.f : 0.f;
            x = m;
        }
        xs[j] = x; ms[j] = m; wsum += x;
    }
    wsum += __shfl_xor(wsum, 1);
    wsum += __shfl_xor(wsum, 2);
    wsum += __shfl_xor(wsum, 4);
    float invd = 1.f / wsum;
    float* prw = out_rw + (size_t)orow * EDIM + e0;
    float* pmk = out_mk + (size_t)orow * EDIM + e0;
    *reinterpret_cast<float4*>(prw)     = make_float4(xs[0]*invd, xs[1]*invd, xs[2]*invd, xs[3]*invd);
    *reinterpret_cast<float4*>(prw + 4) = make_float4(xs[4]*invd, xs[5]*invd, xs[6]*invd, xs[7]*invd);
    *reinterpret_cast<float4*>(pmk)     = make_float4(ms[0], ms[1], ms[2], ms[3]);
    *reinterpret_cast<float4*>(pmk + 4) = make_float4(ms[4], ms[5], ms[6], ms[7]);
}

extern "C" void kernel_launch(void* const* d_in, const int* in_sizes, int n_in,
                              void* d_out, int out_size, void* d_ws, size_t ws_size,
                              hipStream_t stream) {
    const float* H     = (const float*)d_in[0];
    const float* Wm    = (const float*)d_in[1];
    const float* gates = (const float*)d_in[2];
    const int ntok = in_sizes[0] / CDIM;   // 16384

    unsigned short* bfrag = (unsigned short*)d_ws;            // 512 KB
    float* pnw = (float*)(bfrag + (size_t)262144);            // 32 x 64

    float* out_rw = (float*)d_out;
    float* out_lg = out_rw + (size_t)ntok * EDIM;
    float* out_mk = out_lg + (size_t)ntok * EDIM;

    hipLaunchKernelGGL(prep_w, dim3(PREPB), dim3(256), 0, stream, Wm, bfrag, pnw);
    hipLaunchKernelGGL(gating_main, dim3(ntok / BM), dim3(256), 0, stream,
                       H, bfrag, pnw, gates, out_rw, out_lg, out_mk);
}

// Round 15
// 284.575 us; speedup vs baseline: 1.3363x; 1.3363x over previous
//
#include <hip/hip_runtime.h>
#include <math.h>

#define CDIM 2048
#define EDIM 64
#define BM   32
#define NITW 16           // per-wave iterations of BK=32 over its 512-k segment
#define PREPB 32
#define DIAG_REPS 3       // dummy K-passes BEFORE the real one (pressure-identical)

#define SCALE_H 1024.0f
#define SCALE_W 4096.0f
#define INV_SCALE (1.0f / 4194304.0f)

typedef float    f32x16 __attribute__((ext_vector_type(16)));
typedef float    f32x4  __attribute__((ext_vector_type(4)));
typedef _Float16 f16x8  __attribute__((ext_vector_type(8)));
typedef __fp16   cvt_t  __attribute__((ext_vector_type(2)));

// ---- prep: identical to R9
__global__ void prep_w(const float* __restrict__ W,
                       unsigned short* __restrict__ bfrag,
                       float* __restrict__ pnw) {
    __shared__ float tile[64][65];
    __shared__ float part[4][64];
    const int t = threadIdx.x;            // 256
    const int c0 = blockIdx.x * 64;
#pragma unroll
    for (int p = 0; p < 4; ++p) {
        int r = (t >> 4) + p * 16;
        float4 v = *reinterpret_cast<const float4*>(W + (size_t)(c0 + r) * EDIM + (t & 15) * 4);
        tile[r][(t & 15) * 4 + 0] = v.x;
        tile[r][(t & 15) * 4 + 1] = v.y;
        tile[r][(t & 15) * 4 + 2] = v.z;
        tile[r][(t & 15) * 4 + 3] = v.w;
    }
    __syncthreads();
    {
        int g = t >> 6, e = t & 63;
        float s = 0.f;
#pragma unroll
        for (int j = 0; j < 16; ++j) { float v = tile[g * 16 + j][e]; s += v * v; }
        part[g][e] = s;
    }
    __syncthreads();
    if (t < 64) pnw[blockIdx.x * EDIM + t] = part[0][t] + part[1][t] + part[2][t] + part[3][t];
    const int nt = t >> 7, hl = (t >> 6) & 1, lane = t & 63;
    const int e = nt * 32 + (lane & 31);
    const int kb = (lane >> 5) * 8;
#pragma unroll
    for (int s = 0; s < 4; ++s) {
        int kl = s * 16 + kb;
        unsigned int wds[4];
#pragma unroll
        for (int pj = 0; pj < 4; ++pj) {
            float v0 = tile[kl + 2 * pj][e] * SCALE_W;
            float v1 = tile[kl + 2 * pj + 1][e] * SCALE_W;
            cvt_t hh = __builtin_amdgcn_cvt_pkrtz(v0, v1);
            if (hl) {
                cvt_t ll = __builtin_amdgcn_cvt_pkrtz(v0 - (float)hh[0], v1 - (float)hh[1]);
                wds[pj] = __builtin_bit_cast(unsigned int, ll);
            } else {
                wds[pj] = __builtin_bit_cast(unsigned int, hh);
            }
        }
        size_t off = ((size_t)(blockIdx.x * 4 + s)) * 2048 + (size_t)nt * 1024 + (size_t)hl * 512 + (size_t)lane * 8;
        *reinterpret_cast<uint4*>(bfrag + off) = make_uint4(wds[0], wds[1], wds[2], wds[3]);
    }
}

template<int BUF>
__device__ __forceinline__ void stageA(int it, int w, int l, int row0,
    const float* __restrict__ H, float (&aS)[4][2][32][32]) {
#pragma unroll
    for (int J = 0; J < 4; ++J) {
        const int row_ = 8 * J + (l >> 3);
        const float* src = H + (size_t)(row0 + row_) * CDIM + w * 512 + it * 32
                         + (((l & 7) ^ (row_ & 7)) << 2);
        __builtin_amdgcn_global_load_lds(
            (const __attribute__((address_space(1))) unsigned int*)src,
            (__attribute__((address_space(3))) unsigned int*)&aS[w][BUF][8 * J][0], 16, 0, 0);
    }
}

__device__ __forceinline__ void loadB(int it, int w, int l,
    const unsigned short* __restrict__ bfrag, uint4 (&b)[8]) {
    const int kc0 = w * 32 + it * 2;
#pragma unroll
    for (int kc2 = 0; kc2 < 2; ++kc2)
#pragma unroll
        for (int nt = 0; nt < 2; ++nt)
#pragma unroll
            for (int hl = 0; hl < 2; ++hl)
                b[kc2 * 4 + nt * 2 + hl] = *reinterpret_cast<const uint4*>(
                    bfrag + (size_t)(kc0 + kc2) * 2048 + nt * 1024 + hl * 512 + (size_t)l * 8);
}

// R9 kstep verbatim
template<int BUF, bool LAST>
__device__ __forceinline__ void kstep(int it, int w, int l, int row0,
    const float* __restrict__ H, const unsigned short* __restrict__ bfrag,
    float (&aS)[4][2][32][32], f32x16 (&acc)[2], float& nacc) {
    uint4 bcur[8];
    loadB(it, w, l, bfrag, bcur);
    if (!LAST) stageA<BUF ^ 1>(it + 1, w, l, row0, H, aS);
    __builtin_amdgcn_sched_barrier(0);
    if (LAST) { asm volatile("s_waitcnt vmcnt(0)" ::: "memory"); }
    else      { asm volatile("s_waitcnt vmcnt(4)" ::: "memory"); }
    __builtin_amdgcn_sched_barrier(0);

    const int r = l & 31, kg = l >> 5;
#pragma unroll
    for (int kc2 = 0; kc2 < 2; ++kc2) {
        const int c0 = kc2 * 4 + kg * 2;
        f32x4 a0 = *reinterpret_cast<const f32x4*>(&aS[w][BUF][r][((c0)     ^ (r & 7)) * 4]);
        f32x4 a1 = *reinterpret_cast<const f32x4*>(&aS[w][BUF][r][((c0 + 1) ^ (r & 7)) * 4]);
        float f0 = a0[0], f1 = a0[1], f2 = a0[2], f3 = a0[3];
        float f4 = a1[0], f5 = a1[1], f6 = a1[2], f7 = a1[3];
        nacc += f0*f0 + f1*f1 + f2*f2 + f3*f3 + f4*f4 + f5*f5 + f6*f6 + f7*f7;
        float s0 = f0*SCALE_H, s1 = f1*SCALE_H, s2 = f2*SCALE_H, s3 = f3*SCALE_H;
        float s4 = f4*SCALE_H, s5 = f5*SCALE_H, s6 = f6*SCALE_H, s7 = f7*SCALE_H;
        cvt_t h0 = __builtin_amdgcn_cvt_pkrtz(s0, s1);
        cvt_t h1 = __builtin_amdgcn_cvt_pkrtz(s2, s3);
        cvt_t h2 = __builtin_amdgcn_cvt_pkrtz(s4, s5);
        cvt_t h3 = __builtin_amdgcn_cvt_pkrtz(s6, s7);
        cvt_t l0 = __builtin_amdgcn_cvt_pkrtz(s0 - (float)h0[0], s1 - (float)h0[1]);
        cvt_t l1 = __builtin_amdgcn_cvt_pkrtz(s2 - (float)h1[0], s3 - (float)h1[1]);
        cvt_t l2 = __builtin_amdgcn_cvt_pkrtz(s4 - (float)h2[0], s5 - (float)h2[1]);
        cvt_t l3 = __builtin_amdgcn_cvt_pkrtz(s6 - (float)h3[0], s7 - (float)h3[1]);
        f16x8 ah = __builtin_bit_cast(f16x8, make_uint4(
            __builtin_bit_cast(unsigned int, h0), __builtin_bit_cast(unsigned int, h1),
            __builtin_bit_cast(unsigned int, h2), __builtin_bit_cast(unsigned int, h3)));
        f16x8 al = __builtin_bit_cast(f16x8, make_uint4(
            __builtin_bit_cast(unsigned int, l0), __builtin_bit_cast(unsigned int, l1),
            __builtin_bit_cast(unsigned int, l2), __builtin_bit_cast(unsigned int, l3)));
        f16x8 bh0 = __builtin_bit_cast(f16x8, bcur[kc2 * 4 + 0]);
        f16x8 bl0 = __builtin_bit_cast(f16x8, bcur[kc2 * 4 + 1]);
        f16x8 bh1 = __builtin_bit_cast(f16x8, bcur[kc2 * 4 + 2]);
        f16x8 bl1 = __builtin_bit_cast(f16x8, bcur[kc2 * 4 + 3]);
        acc[0] = __builtin_amdgcn_mfma_f32_32x32x16_f16(ah, bh0, acc[0], 0, 0, 0);
        acc[1] = __builtin_amdgcn_mfma_f32_32x32x16_f16(ah, bh1, acc[1], 0, 0, 0);
        acc[0] = __builtin_amdgcn_mfma_f32_32x32x16_f16(ah, bl0, acc[0], 0, 0, 0);
        acc[1] = __builtin_amdgcn_mfma_f32_32x32x16_f16(ah, bl1, acc[1], 0, 0, 0);
        acc[0] = __builtin_amdgcn_mfma_f32_32x32x16_f16(al, bh0, acc[0], 0, 0, 0);
        acc[1] = __builtin_amdgcn_mfma_f32_32x32x16_f16(al, bh1, acc[1], 0, 0, 0);
    }
}

__device__ __forceinline__ void kpass(int w, int l, int row0,
    const float* __restrict__ H, const unsigned short* __restrict__ bfrag,
    float (&aS)[4][2][32][32], f32x16 (&acc)[2], float& nacc) {
    stageA<0>(0, w, l, row0, H, aS);
    kstep<0, false>( 0, w, l, row0, H, bfrag, aS, acc, nacc);
    kstep<1, false>( 1, w, l, row0, H, bfrag, aS, acc, nacc);
    kstep<0, false>( 2, w, l, row0, H, bfrag, aS, acc, nacc);
    kstep<1, false>( 3, w, l, row0, H, bfrag, aS, acc, nacc);
    kstep<0, false>( 4, w, l, row0, H, bfrag, aS, acc, nacc);
    kstep<1, false>( 5, w, l, row0, H, bfrag, aS, acc, nacc);
    kstep<0, false>( 6, w, l, row0, H, bfrag, aS, acc, nacc);
    kstep<1, false>( 7, w, l, row0, H, bfrag, aS, acc, nacc);
    kstep<0, false>( 8, w, l, row0, H, bfrag, aS, acc, nacc);
    kstep<1, false>( 9, w, l, row0, H, bfrag, aS, acc, nacc);
    kstep<0, false>(10, w, l, row0, H, bfrag, aS, acc, nacc);
    kstep<1, false>(11, w, l, row0, H, bfrag, aS, acc, nacc);
    kstep<0, false>(12, w, l, row0, H, bfrag, aS, acc, nacc);
    kstep<1, false>(13, w, l, row0, H, bfrag, aS, acc, nacc);
    kstep<0, false>(14, w, l, row0, H, bfrag, aS, acc, nacc);
    kstep<1, true >(15, w, l, row0, H, bfrag, aS, acc, nacc);
}

// ---- main: 3 dummy passes (same acc -> sink -> rezero; permuted rows) then the real pass.
__launch_bounds__(256, 3)
__global__ void gating_main(const float* __restrict__ H,
                            const unsigned short* __restrict__ bfrag,
                            const float* __restrict__ pnw,
                            const float* __restrict__ gates,
                            float* __restrict__ out_rw,
                            float* __restrict__ out_lg,
                            float* __restrict__ out_mk) {
    __shared__ float aS[4][2][32][32];   // 32 KB; reused as red[4][32][64] after K-loop
    __shared__ float normred[4][32];
    __shared__ float invw_s[64], sig_s[64];

    const int t = threadIdx.x;
    const int w = t >> 6, l = t & 63;
    const int row0 = blockIdx.x * BM;
    const int kg = l >> 5, arow = l & 31;

    f32x16 acc[2];
#pragma unroll
    for (int a = 0; a < 2; ++a)
#pragma unroll
        for (int i = 0; i < 16; ++i) acc[a][i] = 0.f;
    float nacc = 0.f;

    // diagnostic passes: pressure-identical (same acc), results sunk, acc re-zeroed
#pragma unroll 1
    for (int rep = 1; rep <= DIAG_REPS; ++rep) {
        const int rp = (int)(((blockIdx.x + rep * 128u) & 511u) * BM);
        kpass(w, l, rp, H, bfrag, aS, acc, nacc);
        asm volatile("" :: "v"(acc[0][0]), "v"(acc[1][0]), "v"(nacc));
#pragma unroll
        for (int a = 0; a < 2; ++a)
#pragma unroll
            for (int i = 0; i < 16; ++i) acc[a][i] = 0.f;
        nacc = 0.f;
    }

    kpass(w, l, row0, H, bfrag, aS, acc, nacc);          // the real pass

    __syncthreads();                      // all waves' reads done -> reuse aS as red

    float* redp = &aS[0][0][0][0];        // red[(w*32+row)*64 + e]
#pragma unroll
    for (int nt = 0; nt < 2; ++nt)
#pragma unroll
        for (int r = 0; r < 16; ++r) {
            int row = (r & 3) + 8 * (r >> 2) + 4 * kg;   // 32x32 C/D layout
            redp[((size_t)w * 32 + row) * 64 + nt * 32 + arow] = acc[nt][r];
        }
    nacc += __shfl_xor(nacc, 32);
    if (l < 32) normred[w][l] = nacc;
    if (t < 64) {
        float s2 = 0.f;
#pragma unroll
        for (int b = 0; b < PREPB; ++b) s2 += pnw[b * EDIM + t];
        invw_s[t] = 1.f / fmaxf(sqrtf(s2), 1e-12f);
        sig_s[t] = 1.f / (1.f + __expf(-gates[t]));
    }
    __syncthreads();

    const int rr = t >> 3, e0 = (t & 7) * 8;
    const int orow = row0 + rr;
    float nh = normred[0][rr] + normred[1][rr] + normred[2][rr] + normred[3][rr];
    float invh = INV_SCALE / fmaxf(sqrtf(nh), 1e-12f);
    float lg[8];
#pragma unroll
    for (int k2 = 0; k2 < 8; ++k2) {
        int ee = e0 + k2;
        float s = redp[(0 * 32 + rr) * 64 + ee] + redp[(1 * 32 + rr) * 64 + ee]
                + redp[(2 * 32 + rr) * 64 + ee] + redp[(3 * 32 + rr) * 64 + ee];
        lg[k2] = s * invh * invw_s[ee] - sig_s[ee];
    }
    float* plg = out_lg + (size_t)orow * EDIM + e0;
    *reinterpret_cast<float4*>(plg)     = make_float4(lg[0], lg[1], lg[2], lg[3]);
    *reinterpret_cast<float4*>(plg + 4) = make_float4(lg[4], lg[5], lg[6], lg[7]);

    float v1 = -INFINITY, v2 = -INFINITY;
    int i1 = 0x7fffffff, i2 = 0x7fffffff, cnt = 0;
#pragma unroll
    for (int j = 0; j < 8; ++j) {
        int ee = e0 + j;
        float v = lg[j];
        cnt += (v > 0.f) ? 1 : 0;
        if (v > v1) { v2 = v1; i2 = i1; v1 = v; i1 = ee; }
        else if (v > v2) { v2 = v; i2 = ee; }
    }
#pragma unroll
    for (int st = 1; st <= 4; st <<= 1) {
        float w1 = __shfl_xor(v1, st);
        int   j1 = __shfl_xor(i1, st);
        float wv2 = __shfl_xor(v2, st);
        int   j2 = __shfl_xor(i2, st);
        int   cc = __shfl_xor(cnt, st);
        cnt += cc;
        bool g = (w1 > v1) || (w1 == v1 && j1 < i1);
        if (g) {
            bool g2 = (v1 > wv2) || (v1 == wv2 && i1 < j2);
            float nv2 = g2 ? v1 : wv2;
            int   ni2 = g2 ? i1 : j2;
            v1 = w1; i1 = j1; v2 = nv2; i2 = ni2;
        } else {
            bool g2 = (w1 > v2) || (w1 == v2 && j1 < i2);
            if (g2) { v2 = w1; i2 = j1; }
        }
    }
    bool act = cnt > 0;
    float rmax = act ? v1 : 0.f;
    float xs[8], ms[8];
    float wsum = 0.f;
#pragma unroll
    for (int j = 0; j < 8; ++j) {
        int ee = e0 + j;
        float lv = lg[j];
        float x, m;
        if (act) {
            bool sel = lv > 0.f;
            m = sel ? 1.f : 0.f;
            x = sel ? __expf(lv - rmax) : 0.f;
        } else {
            bool sel = (ee == i1) || (ee == i2);
            m = sel ? 1.f : 0.f;
            x = m;
        }
        xs[j] = x; ms[j] = m; wsum += x;
    }
    wsum += __shfl_xor(wsum, 1);
    wsum += __shfl_xor(wsum, 2);
    wsum += __shfl_xor(wsum, 4);
    float invd = 1.f / wsum;
    float* prw = out_rw + (size_t)orow * EDIM + e0;
    float* pmk = out_mk + (size_t)orow * EDIM + e0;
    *reinterpret_cast<float4*>(prw)     = make_float4(xs[0]*invd, xs[1]*invd, xs[2]*invd, xs[3]*invd);
    *reinterpret_cast<float4*>(prw + 4) = make_float4(xs[4]*invd, xs[5]*invd, xs[6]*invd, xs[7]*invd);
    *reinterpret_cast<float4*>(pmk)     = make_float4(ms[0], ms[1], ms[2], ms[3]);
    *reinterpret_cast<float4*>(pmk + 4) = make_float4(ms[4], ms[5], ms[6], ms[7]);
}

extern "C" void kernel_launch(void* const* d_in, const int* in_sizes, int n_in,
                              void* d_out, int out_size, void* d_ws, size_t ws_size,
                              hipStream_t stream) {
    const float* H     = (const float*)d_in[0];
    const float* Wm    = (const float*)d_in[1];
    const float* gates = (const float*)d_in[2];
    const int ntok = in_sizes[0] / CDIM;   // 16384

    unsigned short* bfrag = (unsigned short*)d_ws;            // 512 KB
    float* pnw = (float*)(bfrag + (size_t)262144);            // 32 x 64

    float* out_rw = (float*)d_out;
    float* out_lg = out_rw + (size_t)ntok * EDIM;
    float* out_mk = out_lg + (size_t)ntok * EDIM;

    hipLaunchKernelGGL(prep_w, dim3(PREPB), dim3(256), 0, stream, Wm, bfrag, pnw);
    hipLaunchKernelGGL(gating_main, dim3(ntok / BM), dim3(256), 0, stream,
                       H, bfrag, pnw, gates, out_rw, out_lg, out_mk);
}

// Round 16
// 51.325 us; speedup vs baseline: 7.4089x; 5.5445x over previous
//
#include <hip/hip_runtime.h>
#include <math.h>

#define CDIM 2048
#define EDIM 64
#define BM   32
#define NITW 8            // per-wave iterations of BK=32 over its 256-k segment
#define PREPB 32

#define SCALE_H 1024.0f
#define SCALE_W 4096.0f
#define INV_SCALE (1.0f / 4194304.0f)

typedef float    f32x16 __attribute__((ext_vector_type(16)));
typedef float    f32x4  __attribute__((ext_vector_type(4)));
typedef _Float16 f16x8  __attribute__((ext_vector_type(8)));
typedef __fp16   cvt_t  __attribute__((ext_vector_type(2)));

// ---- prep: identical to R9 (validated)
__global__ void prep_w(const float* __restrict__ W,
                       unsigned short* __restrict__ bfrag,
                       float* __restrict__ pnw) {
    __shared__ float tile[64][65];
    __shared__ float part[4][64];
    const int t = threadIdx.x;            // 256
    const int c0 = blockIdx.x * 64;
#pragma unroll
    for (int p = 0; p < 4; ++p) {
        int r = (t >> 4) + p * 16;
        float4 v = *reinterpret_cast<const float4*>(W + (size_t)(c0 + r) * EDIM + (t & 15) * 4);
        tile[r][(t & 15) * 4 + 0] = v.x;
        tile[r][(t & 15) * 4 + 1] = v.y;
        tile[r][(t & 15) * 4 + 2] = v.z;
        tile[r][(t & 15) * 4 + 3] = v.w;
    }
    __syncthreads();
    {
        int g = t >> 6, e = t & 63;
        float s = 0.f;
#pragma unroll
        for (int j = 0; j < 16; ++j) { float v = tile[g * 16 + j][e]; s += v * v; }
        part[g][e] = s;
    }
    __syncthreads();
    if (t < 64) pnw[blockIdx.x * EDIM + t] = part[0][t] + part[1][t] + part[2][t] + part[3][t];
    const int nt = t >> 7, hl = (t >> 6) & 1, lane = t & 63;
    const int e = nt * 32 + (lane & 31);
    const int kb = (lane >> 5) * 8;
#pragma unroll
    for (int s = 0; s < 4; ++s) {
        int kl = s * 16 + kb;
        unsigned int wds[4];
#pragma unroll
        for (int pj = 0; pj < 4; ++pj) {
            float v0 = tile[kl + 2 * pj][e] * SCALE_W;
            float v1 = tile[kl + 2 * pj + 1][e] * SCALE_W;
            cvt_t hh = __builtin_amdgcn_cvt_pkrtz(v0, v1);
            if (hl) {
                cvt_t ll = __builtin_amdgcn_cvt_pkrtz(v0 - (float)hh[0], v1 - (float)hh[1]);
                wds[pj] = __builtin_bit_cast(unsigned int, ll);
            } else {
                wds[pj] = __builtin_bit_cast(unsigned int, hh);
            }
        }
        size_t off = ((size_t)(blockIdx.x * 4 + s)) * 2048 + (size_t)nt * 1024 + (size_t)hl * 512 + (size_t)lane * 8;
        *reinterpret_cast<uint4*>(bfrag + off) = make_uint4(wds[0], wds[1], wds[2], wds[3]);
    }
}

// A stage: R9 pattern with k-half base
template<int BUF>
__device__ __forceinline__ void stageA(int it, int w, int l, int row0, int kbase,
    const float* __restrict__ H, float (&aS)[4][2][32][32]) {
#pragma unroll
    for (int J = 0; J < 4; ++J) {
        const int row_ = 8 * J + (l >> 3);
        const float* src = H + (size_t)(row0 + row_) * CDIM + kbase + w * 256 + it * 32
                         + (((l & 7) ^ (row_ & 7)) << 2);
        __builtin_amdgcn_global_load_lds(
            (const __attribute__((address_space(1))) unsigned int*)src,
            (__attribute__((address_space(3))) unsigned int*)&aS[w][BUF][8 * J][0], 16, 0, 0);
    }
}

__device__ __forceinline__ void loadB(int it, int w, int l, int kcbase,
    const unsigned short* __restrict__ bfrag, uint4 (&b)[8]) {
    const int kc0 = kcbase + w * 16 + it * 2;
#pragma unroll
    for (int kc2 = 0; kc2 < 2; ++kc2)
#pragma unroll
        for (int nt = 0; nt < 2; ++nt)
#pragma unroll
            for (int hl = 0; hl < 2; ++hl)
                b[kc2 * 4 + nt * 2 + hl] = *reinterpret_cast<const uint4*>(
                    bfrag + (size_t)(kc0 + kc2) * 2048 + nt * 1024 + hl * 512 + (size_t)l * 8);
}

// R9 kstep verbatim (k-half base threaded through)
template<int BUF, bool LAST>
__device__ __forceinline__ void kstep(int it, int w, int l, int row0, int kbase,
    const float* __restrict__ H, const unsigned short* __restrict__ bfrag,
    float (&aS)[4][2][32][32], f32x16 (&acc)[2], float& nacc) {
    uint4 bcur[8];
    loadB(it, w, l, kbase >> 4, bfrag, bcur);
    if (!LAST) stageA<BUF ^ 1>(it + 1, w, l, row0, kbase, H, aS);
    __builtin_amdgcn_sched_barrier(0);
    if (LAST) { asm volatile("s_waitcnt vmcnt(0)" ::: "memory"); }
    else      { asm volatile("s_waitcnt vmcnt(4)" ::: "memory"); }
    __builtin_amdgcn_sched_barrier(0);

    const int r = l & 31, kg = l >> 5;
#pragma unroll
    for (int kc2 = 0; kc2 < 2; ++kc2) {
        const int c0 = kc2 * 4 + kg * 2;
        f32x4 a0 = *reinterpret_cast<const f32x4*>(&aS[w][BUF][r][((c0)     ^ (r & 7)) * 4]);
        f32x4 a1 = *reinterpret_cast<const f32x4*>(&aS[w][BUF][r][((c0 + 1) ^ (r & 7)) * 4]);
        float f0 = a0[0], f1 = a0[1], f2 = a0[2], f3 = a0[3];
        float f4 = a1[0], f5 = a1[1], f6 = a1[2], f7 = a1[3];
        nacc += f0*f0 + f1*f1 + f2*f2 + f3*f3 + f4*f4 + f5*f5 + f6*f6 + f7*f7;
        float s0 = f0*SCALE_H, s1 = f1*SCALE_H, s2 = f2*SCALE_H, s3 = f3*SCALE_H;
        float s4 = f4*SCALE_H, s5 = f5*SCALE_H, s6 = f6*SCALE_H, s7 = f7*SCALE_H;
        cvt_t h0 = __builtin_amdgcn_cvt_pkrtz(s0, s1);
        cvt_t h1 = __builtin_amdgcn_cvt_pkrtz(s2, s3);
        cvt_t h2 = __builtin_amdgcn_cvt_pkrtz(s4, s5);
        cvt_t h3 = __builtin_amdgcn_cvt_pkrtz(s6, s7);
        cvt_t l0 = __builtin_amdgcn_cvt_pkrtz(s0 - (float)h0[0], s1 - (float)h0[1]);
        cvt_t l1 = __builtin_amdgcn_cvt_pkrtz(s2 - (float)h1[0], s3 - (float)h1[1]);
        cvt_t l2 = __builtin_amdgcn_cvt_pkrtz(s4 - (float)h2[0], s5 - (float)h2[1]);
        cvt_t l3 = __builtin_amdgcn_cvt_pkrtz(s6 - (float)h3[0], s7 - (float)h3[1]);
        f16x8 ah = __builtin_bit_cast(f16x8, make_uint4(
            __builtin_bit_cast(unsigned int, h0), __builtin_bit_cast(unsigned int, h1),
            __builtin_bit_cast(unsigned int, h2), __builtin_bit_cast(unsigned int, h3)));
        f16x8 al = __builtin_bit_cast(f16x8, make_uint4(
            __builtin_bit_cast(unsigned int, l0), __builtin_bit_cast(unsigned int, l1),
            __builtin_bit_cast(unsigned int, l2), __builtin_bit_cast(unsigned int, l3)));
        f16x8 bh0 = __builtin_bit_cast(f16x8, bcur[kc2 * 4 + 0]);
        f16x8 bl0 = __builtin_bit_cast(f16x8, bcur[kc2 * 4 + 1]);
        f16x8 bh1 = __builtin_bit_cast(f16x8, bcur[kc2 * 4 + 2]);
        f16x8 bl1 = __builtin_bit_cast(f16x8, bcur[kc2 * 4 + 3]);
        acc[0] = __builtin_amdgcn_mfma_f32_32x32x16_f16(ah, bh0, acc[0], 0, 0, 0);
        acc[1] = __builtin_amdgcn_mfma_f32_32x32x16_f16(ah, bh1, acc[1], 0, 0, 0);
        acc[0] = __builtin_amdgcn_mfma_f32_32x32x16_f16(ah, bl0, acc[0], 0, 0, 0);
        acc[1] = __builtin_amdgcn_mfma_f32_32x32x16_f16(ah, bl1, acc[1], 0, 0, 0);
        acc[0] = __builtin_amdgcn_mfma_f32_32x32x16_f16(al, bh0, acc[0], 0, 0, 0);
        acc[1] = __builtin_amdgcn_mfma_f32_32x32x16_f16(al, bh1, acc[1], 0, 0, 0);
    }
}

// ---- split-K main: grid (512 tiles, 2 k-halves) x 256 thr, 4 independent waves.
//      Per-block traffic: A 16KB/iter-wave (H read once overall), B 256KB (total
//      unchanged at 256MB). Output: partial dots + partial norms.
__launch_bounds__(256, 3)
__global__ void gating_splitk(const float* __restrict__ H,
                              const unsigned short* __restrict__ bfrag,
                              float* __restrict__ pdot,
                              float* __restrict__ pnorm) {
    __shared__ float aS[4][2][32][32];   // 32 KB; reused as red[4][32][64]
    __shared__ float normred[4][32];

    const int t = threadIdx.x;
    const int w = t >> 6, l = t & 63;
    const int row0 = blockIdx.x * BM;
    const int ky = blockIdx.y;
    const int kbase = ky * 1024;
    const int kg = l >> 5, arow = l & 31;

    f32x16 acc[2];
#pragma unroll
    for (int a = 0; a < 2; ++a)
#pragma unroll
        for (int i = 0; i < 16; ++i) acc[a][i] = 0.f;
    float nacc = 0.f;

    stageA<0>(0, w, l, row0, kbase, H, aS);
    kstep<0, false>(0, w, l, row0, kbase, H, bfrag, aS, acc, nacc);
    kstep<1, false>(1, w, l, row0, kbase, H, bfrag, aS, acc, nacc);
    kstep<0, false>(2, w, l, row0, kbase, H, bfrag, aS, acc, nacc);
    kstep<1, false>(3, w, l, row0, kbase, H, bfrag, aS, acc, nacc);
    kstep<0, false>(4, w, l, row0, kbase, H, bfrag, aS, acc, nacc);
    kstep<1, false>(5, w, l, row0, kbase, H, bfrag, aS, acc, nacc);
    kstep<0, false>(6, w, l, row0, kbase, H, bfrag, aS, acc, nacc);
    kstep<1, true >(7, w, l, row0, kbase, H, bfrag, aS, acc, nacc);

    __syncthreads();                      // all waves' reads done -> reuse aS as red

    float* redp = &aS[0][0][0][0];        // red[(w*32+row)*64 + e]
#pragma unroll
    for (int nt = 0; nt < 2; ++nt)
#pragma unroll
        for (int r = 0; r < 16; ++r) {
            int row = (r & 3) + 8 * (r >> 2) + 4 * kg;   // 32x32 C/D layout
            redp[((size_t)w * 32 + row) * 64 + nt * 32 + arow] = acc[nt][r];
        }
    nacc += __shfl_xor(nacc, 32);
    if (l < 32) normred[w][l] = nacc;
    __syncthreads();

    // partial k-half sums (same w0..w3 order as R9) -> global
    const int rr = t >> 3, e0 = (t & 7) * 8;
    float s[8];
#pragma unroll
    for (int j = 0; j < 8; ++j) {
        int e = e0 + j;
        s[j] = redp[(0 * 32 + rr) * 64 + e] + redp[(1 * 32 + rr) * 64 + e]
             + redp[(2 * 32 + rr) * 64 + e] + redp[(3 * 32 + rr) * 64 + e];
    }
    float* pd = pdot + (((size_t)ky * 512 + blockIdx.x) * 32 + rr) * 64 + e0;
    *reinterpret_cast<float4*>(pd)     = make_float4(s[0], s[1], s[2], s[3]);
    *reinterpret_cast<float4*>(pd + 4) = make_float4(s[4], s[5], s[6], s[7]);
    if ((t & 7) == 0)
        pnorm[((size_t)ky * 512 + blockIdx.x) * 32 + rr] =
            normred[0][rr] + normred[1][rr] + normred[2][rr] + normred[3][rr];
}

// ---- fin: sum 2 k-halves, logits, validated top-2/count/softmax, all outputs
__global__ void gating_fin(const float* __restrict__ pdot,
                           const float* __restrict__ pnorm,
                           const float* __restrict__ pnw,
                           const float* __restrict__ gates,
                           float* __restrict__ out_rw,
                           float* __restrict__ out_lg,
                           float* __restrict__ out_mk) {
    __shared__ float invw_s[64], sig_s[64];
    const int t = threadIdx.x;            // 256
    if (t < 64) {
        float s2 = 0.f;
#pragma unroll
        for (int b = 0; b < PREPB; ++b) s2 += pnw[b * EDIM + t];
        invw_s[t] = 1.f / fmaxf(sqrtf(s2), 1e-12f);
        sig_s[t] = 1.f / (1.f + __expf(-gates[t]));
    }
    __syncthreads();

    const int rr = t >> 3, e0 = (t & 7) * 8;
    const int orow = blockIdx.x * 32 + rr;
    float nh = pnorm[((size_t)0 * 512 + blockIdx.x) * 32 + rr]
             + pnorm[((size_t)1 * 512 + blockIdx.x) * 32 + rr];
    float invh = INV_SCALE / fmaxf(sqrtf(nh), 1e-12f);

    const float* pd0 = pdot + (((size_t)0 * 512 + blockIdx.x) * 32 + rr) * 64 + e0;
    const float* pd1 = pdot + (((size_t)1 * 512 + blockIdx.x) * 32 + rr) * 64 + e0;
    float lg[8];
#pragma unroll
    for (int i = 0; i < 2; ++i) {
        float4 a = *reinterpret_cast<const float4*>(pd0 + i * 4);
        float4 b = *reinterpret_cast<const float4*>(pd1 + i * 4);
        lg[i*4+0] = a.x + b.x; lg[i*4+1] = a.y + b.y;
        lg[i*4+2] = a.z + b.z; lg[i*4+3] = a.w + b.w;
    }
#pragma unroll
    for (int j = 0; j < 8; ++j) {
        int ee = e0 + j;
        lg[j] = lg[j] * invh * invw_s[ee] - sig_s[ee];
    }
    float* plg = out_lg + (size_t)orow * EDIM + e0;
    *reinterpret_cast<float4*>(plg)     = make_float4(lg[0], lg[1], lg[2], lg[3]);
    *reinterpret_cast<float4*>(plg + 4) = make_float4(lg[4], lg[5], lg[6], lg[7]);

    float v1 = -INFINITY, v2 = -INFINITY;
    int i1 = 0x7fffffff, i2 = 0x7fffffff, cnt = 0;
#pragma unroll
    for (int j = 0; j < 8; ++j) {
        int ee = e0 + j;
        float v = lg[j];
        cnt += (v > 0.f) ? 1 : 0;
        if (v > v1) { v2 = v1; i2 = i1; v1 = v; i1 = ee; }
        else if (v > v2) { v2 = v; i2 = ee; }
    }
#pragma unroll
    for (int st = 1; st <= 4; st <<= 1) {
        float w1 = __shfl_xor(v1, st);
        int   j1 = __shfl_xor(i1, st);
        float wv2 = __shfl_xor(v2, st);
        int   j2 = __shfl_xor(i2, st);
        int   cc = __shfl_xor(cnt, st);
        cnt += cc;
        bool g = (w1 > v1) || (w1 == v1 && j1 < i1);
        if (g) {
            bool g2 = (v1 > wv2) || (v1 == wv2 && i1 < j2);
            float nv2 = g2 ? v1 : wv2;
            int   ni2 = g2 ? i1 : j2;
            v1 = w1; i1 = j1; v2 = nv2; i2 = ni2;
        } else {
            bool g2 = (w1 > v2) || (w1 == v2 && j1 < i2);
            if (g2) { v2 = w1; i2 = j1; }
        }
    }
    bool act = cnt > 0;
    float rmax = act ? v1 : 0.f;
    float xs[8], ms[8];
    float wsum = 0.f;
#pragma unroll
    for (int j = 0; j < 8; ++j) {
        int ee = e0 + j;
        float lv = lg[j];
        float x, m;
        if (act) {
            bool sel = lv > 0.f;
            m = sel ? 1.f : 0.f;
            x = sel ? __expf(lv - rmax) : 0.f;
        } else {
            bool sel = (ee == i1) || (ee == i2);
            m = sel ? 1.f : 0.f;
            x = m;
        }
        xs[j] = x; ms[j] = m; wsum += x;
    }
    wsum += __shfl_xor(wsum, 1);
    wsum += __shfl_xor(wsum, 2);
    wsum += __shfl_xor(wsum, 4);
    float invd = 1.f / wsum;
    float* prw = out_rw + (size_t)orow * EDIM + e0;
    float* pmk = out_mk + (size_t)orow * EDIM + e0;
    *reinterpret_cast<float4*>(prw)     = make_float4(xs[0]*invd, xs[1]*invd, xs[2]*invd, xs[3]*invd);
    *reinterpret_cast<float4*>(prw + 4) = make_float4(xs[4]*invd, xs[5]*invd, xs[6]*invd, xs[7]*invd);
    *reinterpret_cast<float4*>(pmk)     = make_float4(ms[0], ms[1], ms[2], ms[3]);
    *reinterpret_cast<float4*>(pmk + 4) = make_float4(ms[4], ms[5], ms[6], ms[7]);
}

extern "C" void kernel_launch(void* const* d_in, const int* in_sizes, int n_in,
                              void* d_out, int out_size, void* d_ws, size_t ws_size,
                              hipStream_t stream) {
    const float* H     = (const float*)d_in[0];
    const float* Wm    = (const float*)d_in[1];
    const float* gates = (const float*)d_in[2];
    const int ntok = in_sizes[0] / CDIM;   // 16384
    const int nmb  = ntok / BM;            // 512

    unsigned short* bfrag = (unsigned short*)d_ws;            // 512 KB
    float* pnw   = (float*)(bfrag + (size_t)262144);          // 32 x 64
    float* pdot  = pnw + 32 * 64;                             // 2 x 512 x 32 x 64
    float* pnorm = pdot + (size_t)2 * 512 * 32 * 64;          // 2 x 512 x 32

    float* out_rw = (float*)d_out;
    float* out_lg = out_rw + (size_t)ntok * EDIM;
    float* out_mk = out_lg + (size_t)ntok * EDIM;

    hipLaunchKernelGGL(prep_w, dim3(PREPB), dim3(256), 0, stream, Wm, bfrag, pnw);
    hipLaunchKernelGGL(gating_splitk, dim3(nmb, 2), dim3(256), 0, stream,
                       H, bfrag, pdot, pnorm);
    hipLaunchKernelGGL(gating_fin, dim3(nmb), dim3(256), 0, stream,
                       pdot, pnorm, pnw, gates, out_rw, out_lg, out_mk);
}

// Round 17
// 35.891 us; speedup vs baseline: 10.5950x; 1.4300x over previous
//
#include <hip/hip_runtime.h>
#include <math.h>

#define CDIM 2048
#define EDIM 64
#define BM   32
#define NITW 16           // per-wave iterations of BK=32 over its 512-k segment
#define PREPB 32

// scales keep fp16 "lo" parts normal; product scale = 2^22
#define SCALE_H 1024.0f
#define SCALE_W 4096.0f
#define INV_SCALE (1.0f / 4194304.0f)

typedef float    f32x16 __attribute__((ext_vector_type(16)));
typedef float    f32x4  __attribute__((ext_vector_type(4)));
typedef _Float16 f16x8  __attribute__((ext_vector_type(8)));
typedef __fp16   cvt_t  __attribute__((ext_vector_type(2)));

// ---- prep: 32 blocks x 64 k-rows. Coalesced W load, LDS transpose, col-norm partials,
//      fragment-order B for 32x32x16: bfrag[kc][nt][hl][lane][8 halves], kc=k/16;
//      lane l supplies B[k=kc*16+(l>>5)*8+j][e=nt*32+(l&31)]. 512 KB, L2-resident.
__global__ void prep_w(const float* __restrict__ W,
                       unsigned short* __restrict__ bfrag,
                       float* __restrict__ pnw) {
    __shared__ float tile[64][65];
    __shared__ float part[4][64];
    const int t = threadIdx.x;            // 256
    const int c0 = blockIdx.x * 64;
#pragma unroll
    for (int p = 0; p < 4; ++p) {
        int r = (t >> 4) + p * 16;
        float4 v = *reinterpret_cast<const float4*>(W + (size_t)(c0 + r) * EDIM + (t & 15) * 4);
        tile[r][(t & 15) * 4 + 0] = v.x;
        tile[r][(t & 15) * 4 + 1] = v.y;
        tile[r][(t & 15) * 4 + 2] = v.z;
        tile[r][(t & 15) * 4 + 3] = v.w;
    }
    __syncthreads();
    {
        int g = t >> 6, e = t & 63;
        float s = 0.f;
#pragma unroll
        for (int j = 0; j < 16; ++j) { float v = tile[g * 16 + j][e]; s += v * v; }
        part[g][e] = s;
    }
    __syncthreads();
    if (t < 64) pnw[blockIdx.x * EDIM + t] = part[0][t] + part[1][t] + part[2][t] + part[3][t];
    const int nt = t >> 7, hl = (t >> 6) & 1, lane = t & 63;
    const int e = nt * 32 + (lane & 31);
    const int kb = (lane >> 5) * 8;
#pragma unroll
    for (int s = 0; s < 4; ++s) {
        int kl = s * 16 + kb;
        unsigned int wds[4];
#pragma unroll
        for (int pj = 0; pj < 4; ++pj) {
            float v0 = tile[kl + 2 * pj][e] * SCALE_W;
            float v1 = tile[kl + 2 * pj + 1][e] * SCALE_W;
            cvt_t hh = __builtin_amdgcn_cvt_pkrtz(v0, v1);
            if (hl) {
                cvt_t ll = __builtin_amdgcn_cvt_pkrtz(v0 - (float)hh[0], v1 - (float)hh[1]);
                wds[pj] = __builtin_bit_cast(unsigned int, ll);
            } else {
                wds[pj] = __builtin_bit_cast(unsigned int, hh);
            }
        }
        size_t off = ((size_t)(blockIdx.x * 4 + s)) * 2048 + (size_t)nt * 1024 + (size_t)hl * 512 + (size_t)lane * 8;
        *reinterpret_cast<uint4*>(bfrag + off) = make_uint4(wds[0], wds[1], wds[2], wds[3]);
    }
}

// A stage: 32 rows x 32 k fp32 -> wave-private LDS buf (4 insts x 1 KB, linear dest,
// source 16B-chunk XOR-preswizzled so read-side swizzle is bank-spread)
template<int BUF>
__device__ __forceinline__ void stageA(int it, int w, int l, int row0,
    const float* __restrict__ H, float (&aS)[4][2][32][32]) {
#pragma unroll
    for (int J = 0; J < 4; ++J) {
        const int row_ = 8 * J + (l >> 3);
        const float* src = H + (size_t)(row0 + row_) * CDIM + w * 512 + it * 32
                         + (((l & 7) ^ (row_ & 7)) << 2);
        __builtin_amdgcn_global_load_lds(
            (const __attribute__((address_space(1))) unsigned int*)src,
            (__attribute__((address_space(3))) unsigned int*)&aS[w][BUF][8 * J][0], 16, 0, 0);
    }
}

// B load: 8 contiguous dwordx4 per lane from fragment-ordered bfrag (L2-hot)
__device__ __forceinline__ void loadB(int it, int w, int l,
    const unsigned short* __restrict__ bfrag, uint4 (&b)[8]) {
    const int kc0 = w * 32 + it * 2;
#pragma unroll
    for (int kc2 = 0; kc2 < 2; ++kc2)
#pragma unroll
        for (int nt = 0; nt < 2; ++nt)
#pragma unroll
            for (int hl = 0; hl < 2; ++hl)
                b[kc2 * 4 + nt * 2 + hl] = *reinterpret_cast<const uint4*>(
                    bfrag + (size_t)(kc0 + kc2) * 2048 + nt * 1024 + hl * 512 + (size_t)l * 8);
}

// one K-step: loadB(it) THEN stageA(it+1) THEN vmcnt(4) (retires A(it)+B(it),
// leaves A(it+1) in flight across the whole compute). No barriers; waves independent.
template<int BUF, bool LAST>
__device__ __forceinline__ void kstep(int it, int w, int l, int row0,
    const float* __restrict__ H, const unsigned short* __restrict__ bfrag,
    float (&aS)[4][2][32][32], f32x16 (&acc)[2], float& nacc) {
    uint4 bcur[8];
    loadB(it, w, l, bfrag, bcur);
    if (!LAST) stageA<BUF ^ 1>(it + 1, w, l, row0, H, aS);
    __builtin_amdgcn_sched_barrier(0);
    if (LAST) { asm volatile("s_waitcnt vmcnt(0)" ::: "memory"); }
    else      { asm volatile("s_waitcnt vmcnt(4)" ::: "memory"); }
    __builtin_amdgcn_sched_barrier(0);

    const int r = l & 31, kg = l >> 5;
#pragma unroll
    for (int kc2 = 0; kc2 < 2; ++kc2) {
        const int c0 = kc2 * 4 + kg * 2;
        f32x4 a0 = *reinterpret_cast<const f32x4*>(&aS[w][BUF][r][((c0)     ^ (r & 7)) * 4]);
        f32x4 a1 = *reinterpret_cast<const f32x4*>(&aS[w][BUF][r][((c0 + 1) ^ (r & 7)) * 4]);
        float f0 = a0[0], f1 = a0[1], f2 = a0[2], f3 = a0[3];
        float f4 = a1[0], f5 = a1[1], f6 = a1[2], f7 = a1[3];
        nacc += f0*f0 + f1*f1 + f2*f2 + f3*f3 + f4*f4 + f5*f5 + f6*f6 + f7*f7;
        float s0 = f0*SCALE_H, s1 = f1*SCALE_H, s2 = f2*SCALE_H, s3 = f3*SCALE_H;
        float s4 = f4*SCALE_H, s5 = f5*SCALE_H, s6 = f6*SCALE_H, s7 = f7*SCALE_H;
        cvt_t h0 = __builtin_amdgcn_cvt_pkrtz(s0, s1);
        cvt_t h1 = __builtin_amdgcn_cvt_pkrtz(s2, s3);
        cvt_t h2 = __builtin_amdgcn_cvt_pkrtz(s4, s5);
        cvt_t h3 = __builtin_amdgcn_cvt_pkrtz(s6, s7);
        cvt_t l0 = __builtin_amdgcn_cvt_pkrtz(s0 - (float)h0[0], s1 - (float)h0[1]);
        cvt_t l1 = __builtin_amdgcn_cvt_pkrtz(s2 - (float)h1[0], s3 - (float)h1[1]);
        cvt_t l2 = __builtin_amdgcn_cvt_pkrtz(s4 - (float)h2[0], s5 - (float)h2[1]);
        cvt_t l3 = __builtin_amdgcn_cvt_pkrtz(s6 - (float)h3[0], s7 - (float)h3[1]);
        f16x8 ah = __builtin_bit_cast(f16x8, make_uint4(
            __builtin_bit_cast(unsigned int, h0), __builtin_bit_cast(unsigned int, h1),
            __builtin_bit_cast(unsigned int, h2), __builtin_bit_cast(unsigned int, h3)));
        f16x8 al = __builtin_bit_cast(f16x8, make_uint4(
            __builtin_bit_cast(unsigned int, l0), __builtin_bit_cast(unsigned int, l1),
            __builtin_bit_cast(unsigned int, l2), __builtin_bit_cast(unsigned int, l3)));
        f16x8 bh0 = __builtin_bit_cast(f16x8, bcur[kc2 * 4 + 0]);
        f16x8 bl0 = __builtin_bit_cast(f16x8, bcur[kc2 * 4 + 1]);
        f16x8 bh1 = __builtin_bit_cast(f16x8, bcur[kc2 * 4 + 2]);
        f16x8 bl1 = __builtin_bit_cast(f16x8, bcur[kc2 * 4 + 3]);
        // all three split terms accumulate into the same per-nt acc
        acc[0] = __builtin_amdgcn_mfma_f32_32x32x16_f16(ah, bh0, acc[0], 0, 0, 0);
        acc[1] = __builtin_amdgcn_mfma_f32_32x32x16_f16(ah, bh1, acc[1], 0, 0, 0);
        acc[0] = __builtin_amdgcn_mfma_f32_32x32x16_f16(ah, bl0, acc[0], 0, 0, 0);
        acc[1] = __builtin_amdgcn_mfma_f32_32x32x16_f16(ah, bl1, acc[1], 0, 0, 0);
        acc[0] = __builtin_amdgcn_mfma_f32_32x32x16_f16(al, bh0, acc[0], 0, 0, 0);
        acc[1] = __builtin_amdgcn_mfma_f32_32x32x16_f16(al, bh1, acc[1], 0, 0, 0);
    }
}

// ---- main: 512 blocks x 256 thr, 4 independent waves (wave w = k-segment w).
__launch_bounds__(256, 3)
__global__ void gating_main(const float* __restrict__ H,
                            const unsigned short* __restrict__ bfrag,
                            const float* __restrict__ pnw,
                            const float* __restrict__ gates,
                            float* __restrict__ out_rw,
                            float* __restrict__ out_lg,
                            float* __restrict__ out_mk) {
    __shared__ float aS[4][2][32][32];   // 32 KB; reused as red[4][32][64] after K-loop
    __shared__ float normred[4][32];
    __shared__ float invw_s[64], sig_s[64];

    const int t = threadIdx.x;
    const int w = t >> 6, l = t & 63;
    const int row0 = blockIdx.x * BM;
    const int kg = l >> 5, arow = l & 31;

    f32x16 acc[2];
#pragma unroll
    for (int a = 0; a < 2; ++a)
#pragma unroll
        for (int i = 0; i < 16; ++i) acc[a][i] = 0.f;
    float nacc = 0.f;

    stageA<0>(0, w, l, row0, H, aS);
#pragma unroll
    for (int ot = 0; ot < 7; ++ot) {
        kstep<0, false>(2 * ot,     w, l, row0, H, bfrag, aS, acc, nacc);
        kstep<1, false>(2 * ot + 1, w, l, row0, H, bfrag, aS, acc, nacc);
    }
    kstep<0, false>(14, w, l, row0, H, bfrag, aS, acc, nacc);
    kstep<1, true >(15, w, l, row0, H, bfrag, aS, acc, nacc);

    __syncthreads();                      // all waves' reads done -> reuse aS as red

    float* redp = &aS[0][0][0][0];        // red[(w*32+row)*64 + e]
#pragma unroll
    for (int nt = 0; nt < 2; ++nt)
#pragma unroll
        for (int r = 0; r < 16; ++r) {
            int row = (r & 3) + 8 * (r >> 2) + 4 * kg;   // 32x32 C/D layout
            redp[((size_t)w * 32 + row) * 64 + nt * 32 + arow] = acc[nt][r];
        }
    nacc += __shfl_xor(nacc, 32);
    if (l < 32) normred[w][l] = nacc;
    if (t < 64) {
        float s2 = 0.f;
#pragma unroll
        for (int b = 0; b < PREPB; ++b) s2 += pnw[b * EDIM + t];
        invw_s[t] = 1.f / fmaxf(sqrtf(s2), 1e-12f);
        sig_s[t] = 1.f / (1.f + __expf(-gates[t]));
    }
    __syncthreads();

    // ---- epilogue: 8 threads per row, 8 experts each (validated top-2/count/softmax)
    const int rr = t >> 3, e0 = (t & 7) * 8;
    const int orow = row0 + rr;
    float nh = normred[0][rr] + normred[1][rr] + normred[2][rr] + normred[3][rr];
    float invh = INV_SCALE / fmaxf(sqrtf(nh), 1e-12f);
    float lg[8];
#pragma unroll
    for (int k2 = 0; k2 < 8; ++k2) {
        int ee = e0 + k2;
        float s = redp[(0 * 32 + rr) * 64 + ee] + redp[(1 * 32 + rr) * 64 + ee]
                + redp[(2 * 32 + rr) * 64 + ee] + redp[(3 * 32 + rr) * 64 + ee];
        lg[k2] = s * invh * invw_s[ee] - sig_s[ee];
    }
    float* plg = out_lg + (size_t)orow * EDIM + e0;
    *reinterpret_cast<float4*>(plg)     = make_float4(lg[0], lg[1], lg[2], lg[3]);
    *reinterpret_cast<float4*>(plg + 4) = make_float4(lg[4], lg[5], lg[6], lg[7]);

    float v1 = -INFINITY, v2 = -INFINITY;
    int i1 = 0x7fffffff, i2 = 0x7fffffff, cnt = 0;
#pragma unroll
    for (int j = 0; j < 8; ++j) {
        int ee = e0 + j;
        float v = lg[j];
        cnt += (v > 0.f) ? 1 : 0;
        if (v > v1) { v2 = v1; i2 = i1; v1 = v; i1 = ee; }
        else if (v > v2) { v2 = v; i2 = ee; }
    }
#pragma unroll
    for (int st = 1; st <= 4; st <<= 1) {
        float w1 = __shfl_xor(v1, st);
        int   j1 = __shfl_xor(i1, st);
        float wv2 = __shfl_xor(v2, st);
        int   j2 = __shfl_xor(i2, st);
        int   cc = __shfl_xor(cnt, st);
        cnt += cc;
        bool g = (w1 > v1) || (w1 == v1 && j1 < i1);
        if (g) {
            bool g2 = (v1 > wv2) || (v1 == wv2 && i1 < j2);
            float nv2 = g2 ? v1 : wv2;
            int   ni2 = g2 ? i1 : j2;
            v1 = w1; i1 = j1; v2 = nv2; i2 = ni2;
        } else {
            bool g2 = (w1 > v2) || (w1 == v2 && j1 < i2);
            if (g2) { v2 = w1; i2 = j1; }
        }
    }
    bool act = cnt > 0;
    float rmax = act ? v1 : 0.f;
    float xs[8], ms[8];
    float wsum = 0.f;
#pragma unroll
    for (int j = 0; j < 8; ++j) {
        int ee = e0 + j;
        float lv = lg[j];
        float x, m;
        if (act) {
            bool sel = lv > 0.f;
            m = sel ? 1.f : 0.f;
            x = sel ? __expf(lv - rmax) : 0.f;
        } else {
            bool sel = (ee == i1) || (ee == i2);
            m = sel ? 1.f : 0.f;
            x = m;
        }
        xs[j] = x; ms[j] = m; wsum += x;
    }
    wsum += __shfl_xor(wsum, 1);
    wsum += __shfl_xor(wsum, 2);
    wsum += __shfl_xor(wsum, 4);
    float invd = 1.f / wsum;
    float* prw = out_rw + (size_t)orow * EDIM + e0;
    float* pmk = out_mk + (size_t)orow * EDIM + e0;
    *reinterpret_cast<float4*>(prw)     = make_float4(xs[0]*invd, xs[1]*invd, xs[2]*invd, xs[3]*invd);
    *reinterpret_cast<float4*>(prw + 4) = make_float4(xs[4]*invd, xs[5]*invd, xs[6]*invd, xs[7]*invd);
    *reinterpret_cast<float4*>(pmk)     = make_float4(ms[0], ms[1], ms[2], ms[3]);
    *reinterpret_cast<float4*>(pmk + 4) = make_float4(ms[4], ms[5], ms[6], ms[7]);
}

extern "C" void kernel_launch(void* const* d_in, const int* in_sizes, int n_in,
                              void* d_out, int out_size, void* d_ws, size_t ws_size,
                              hipStream_t stream) {
    const float* H     = (const float*)d_in[0];
    const float* Wm    = (const float*)d_in[1];
    const float* gates = (const float*)d_in[2];
    const int ntok = in_sizes[0] / CDIM;   // 16384

    unsigned short* bfrag = (unsigned short*)d_ws;            // 512 KB
    float* pnw = (float*)(bfrag + (size_t)262144);            // 32 x 64

    float* out_rw = (float*)d_out;
    float* out_lg = out_rw + (size_t)ntok * EDIM;
    float* out_mk = out_lg + (size_t)ntok * EDIM;

    hipLaunchKernelGGL(prep_w, dim3(PREPB), dim3(256), 0, stream, Wm, bfrag, pnw);
    hipLaunchKernelGGL(gating_main, dim3(ntok / BM), dim3(256), 0, stream,
                       H, bfrag, pnw, gates, out_rw, out_lg, out_mk);
}